// Round 10
// baseline (267.244 us; speedup 1.0000x reference)
//
#include <hip/hip_runtime.h>

// Problem dims (fixed by setup_inputs)
#define HH 384
#define WW 512
#define NB 4
#define HWP (HH * WW)       // 196608
#define NPIX (NB * HWP)     // 786432
#define SH 96
#define SW 128
#define SHW (SH * SW)

// Row-banded gather parameters
#define MBOUND 24           // |fy| < 24 handled by banded gather; rest -> exact overflow list
#define BAND 4              // target rows per block
#define NBANDS (HH / BAND)  // 96
#define NROWS (BAND + 3)    // LDS rows t0-2 .. t0+4 (halo for in-LDS fill)
#define OV_CAP 131072       // overflow record capacity (expected ~3-6K used; >20x margin)

// Strict-IEEE f32 bilinear 4x upsample of (10*flow) — bit-identical to the
// passing version. Do not touch: floor decisions depend on it.
static __device__ __forceinline__ float upsample_flow_f32(const float* __restrict__ f, int y, int x) {
    float sx = __fadd_rn(__fmul_rn((float)x, 0.25f), -0.375f);  // exact
    float sy = __fadd_rn(__fmul_rn((float)y, 0.25f), -0.375f);  // exact
    float fx0 = floorf(sx), fy0 = floorf(sy);
    float wx = __fsub_rn(sx, fx0);   // exact: {0.625,0.875,0.125,0.375}
    float wy = __fsub_rn(sy, fy0);
    int ix = (int)fx0, iy = (int)fy0;
    int x0 = max(ix, 0), x1 = min(ix + 1, SW - 1);
    int y0 = max(iy, 0), y1 = min(iy + 1, SH - 1);
    float v00 = __fmul_rn(10.0f, f[y0 * SW + x0]);
    float v01 = __fmul_rn(10.0f, f[y0 * SW + x1]);
    float v10 = __fmul_rn(10.0f, f[y1 * SW + x0]);
    float v11 = __fmul_rn(10.0f, f[y1 * SW + x1]);
    float omx = __fsub_rn(1.0f, wx);
    float omy = __fsub_rn(1.0f, wy);
    float w00 = __fmul_rn(omx, omy);
    float w10 = __fmul_rn(wx, omy);
    float w01 = __fmul_rn(omx, wy);
    float w11 = __fmul_rn(wx, wy);
    float s = __fmul_rn(w00, v00);
    s = __fadd_rn(s, __fmul_rn(w10, v01));
    s = __fadd_rn(s, __fmul_rn(w01, v10));
    s = __fadd_rn(s, __fmul_rn(w11, v11));
    return s;
}

// Phase 1: materialize upsampled flow (plain coalesced stores, no atomics).
// Fu layout: [side][comp][b][h][w]. Valid pixels with |fy|>=MBOUND go to an
// exact overflow list in the workspace (counter @ovf[0], keys @+64 ints,
// vx @+64+OV_CAP, vy @+64+2*OV_CAP).
__global__ __launch_bounds__(256) void upsample_k(const float* __restrict__ flow01,
                                                  const float* __restrict__ flow10,
                                                  float* __restrict__ Fu, float* __restrict__ ovf) {
    int idx = blockIdx.x * blockDim.x + threadIdx.x;
    if (idx >= NPIX) return;
    int side = blockIdx.y;
    const float* flow = side ? flow10 : flow01;
    int x = idx % WW;
    int y = (idx / WW) % HH;
    int b = idx / HWP;
    const float* fp = flow + b * 2 * SHW;
    float fx = upsample_flow_f32(fp, y, x);
    float fy = upsample_flow_f32(fp + SHW, y, x);
    float* F = Fu + side * 2 * NPIX;
    F[idx] = fx;
    F[NPIX + idx] = fy;
    float x2 = __fadd_rn((float)x, fx);
    float y2 = __fadd_rn((float)y, fy);
    bool valid = (x2 >= 0.0f && x2 <= (float)(WW - 1) && y2 >= 0.0f && y2 <= (float)(HH - 1));
    bool banded = (fy >= -(float)MBOUND && fy < (float)MBOUND);
    if (valid && !banded) {
        int xf = (int)floorf(x2);
        int yf = (int)floorf(y2);
        int key = side * NPIX + b * HWP + yf * WW + xf;
        int slot = atomicAdd((int*)ovf, 1);
        if (slot >= 0 && slot < OV_CAP) {
            ((int*)ovf)[64 + slot] = key;
            ovf[64 + OV_CAP + slot] = -fx;
            ovf[64 + 2 * OV_CAP + slot] = -fy;
        }
    }
}

// 2x2 weighted box-sum over the LDS band histogram == the reference's
// 4-neighbor scatter sum. Identical add order/weights to the proven global
// version; only the storage moved to LDS.
static __device__ __forceinline__ void box_sum_lds(const float (&acc)[3][NROWS][WW], int rbase,
                                                   int y, int x, float& ax, float& ay, float& c) {
    float wxs1 = (x == WW - 1) ? 2.0f : 1.0f;
    float wys1 = (y == HH - 1) ? 2.0f : 1.0f;
    float sx = 0.0f, sy = 0.0f, sc = 0.0f;
    #pragma unroll
    for (int j = 0; j < 2; j++) {
        int ey = y - 1 + j;
        if (ey < 0) continue;
        float wy = j ? wys1 : 1.0f;
        int rr = ey - rbase;   // in [0, NROWS-1] by construction
        #pragma unroll
        for (int i = 0; i < 2; i++) {
            int ex = x - 1 + i;
            if (ex < 0) continue;
            float w = wy * ((i ? wxs1 : 1.0f));   // exact
            sx += w * acc[0][rr][ex];
            sy += w * acc[1][rr][ex];
            sc += w * acc[2][rr][ex];
        }
    }
    ax = sx; ay = sy; c = sc;
}

// Phase 2 (fully fused): one block per (side, b, 4-row band), 512 threads.
// (a) Build the deposit histogram for rows [t0-2, t0+4] in LDS (LDS atomics,
// float4 scan loads: 4 px per work item), (b) replay the exact overflow
// list, (c) per pixel: in-LDS fill -> Ft, then the 4x4-filter bilinear
// interp, atomically combining 0.5*acc into out (memset-zeroed).
// LDS 43 KB -> 3 blocks/CU; 768 blocks = exactly 3/CU all-resident, no tail.
// __launch_bounds__(512, 6): 6 waves/SIMD keeps VGPR <= 85 for 3 blocks/CU.
// XCD-chunked blockIdx mapping (slab = bid&7) keeps each slab L2-resident.
__global__ __launch_bounds__(512, 6) void rgf_interp_k(const float* __restrict__ Fu,
                                                       const float* __restrict__ ovf,
                                                       const float* __restrict__ img0,
                                                       const float* __restrict__ img2,
                                                       const float* __restrict__ filt0,
                                                       const float* __restrict__ filt1,
                                                       float* __restrict__ out) {
    __shared__ float acc[3][NROWS][WW];   // 43 KB
    int bid = blockIdx.x;                 // 768 blocks
    int slab = bid & 7;
    int side = slab >> 2;
    int b = slab & 3;
    int t0 = (bid >> 3) * BAND;
    int rbase = t0 - 2;                   // global row of acc row 0

    const float* Fx = Fu + side * 2 * NPIX + b * HWP;
    const float* Fyp = Fx + NPIX;

    float* A = &acc[0][0][0];
    for (int k = threadIdx.x; k < 3 * NROWS * WW; k += 512) A[k] = 0.0f;
    __syncthreads();

    // sources for target rows [t0-2, t0+BAND] with floor(fy) in [-M, M-1]:
    // s in [t0-2-(M-1), t0+BAND+M]  (54 rows interior)
    int sLo = max(t0 - 2 - (MBOUND - 1), 0);
    int sHi = min(t0 + BAND + MBOUND, HH - 1);
    int nitems = (sHi - sLo + 1) * 128;   // (row, col-quad) work items
    for (int k = threadIdx.x; k < nitems; k += 512) {
        int s = sLo + (k >> 7);
        int tx = k & 127;
        int rowoff = s * WW + 4 * tx;
        float4 fxv = *(const float4*)(Fx + rowoff);
        float4 fyv = *(const float4*)(Fyp + rowoff);
        float sf = (float)s;
        #pragma unroll
        for (int u = 0; u < 4; ++u) {
            int xx = 4 * tx + u;
            float fx = (u == 0) ? fxv.x : (u == 1) ? fxv.y : (u == 2) ? fxv.z : fxv.w;
            float fy = (u == 0) ? fyv.x : (u == 1) ? fyv.y : (u == 2) ? fyv.z : fyv.w;
            float x2 = __fadd_rn((float)xx, fx);
            float y2 = __fadd_rn(sf, fy);
            if (x2 >= 0.0f && x2 <= (float)(WW - 1) && y2 >= 0.0f && y2 <= (float)(HH - 1)
                && fy >= -(float)MBOUND && fy < (float)MBOUND) {
                int yf = (int)floorf(y2);
                int r = yf - rbase;
                if (r >= 0 && r < NROWS) {
                    int xf = (int)floorf(x2);
                    atomicAdd(&acc[0][r][xf], -fx);
                    atomicAdd(&acc[1][r][xf], -fy);
                    atomicAdd(&acc[2][r][xf], 1.0f);
                }
            }
        }
    }

    // replay exact overflow records landing in [max(rbase,0), min(t0+BAND,HH-1)]
    int n = ((const int*)ovf)[0];
    n = (n < 0) ? 0 : ((n > OV_CAP) ? OV_CAP : n);
    int lo = max(rbase, 0) * WW;
    int hi = (min(t0 + BAND, HH - 1) + 1) * WW;
    int keybase = side * NPIX + b * HWP;
    for (int i = threadIdx.x; i < n; i += 512) {
        int rel = ((const int*)ovf)[64 + i] - keybase;
        if (rel >= lo && rel < hi) {
            int r = rel / WW - rbase;
            int xf = rel % WW;
            atomicAdd(&acc[0][r][xf], ovf[64 + OV_CAP + i]);
            atomicAdd(&acc[1][r][xf], ovf[64 + 2 * OV_CAP + i]);
            atomicAdd(&acc[2][r][xf], 1.0f);
        }
    }
    __syncthreads();

    // (c) per-pixel fill + interp. Thread = column x, loop j over the 4 band
    // rows. acc is read-only from here (no further syncs needed).
    const float* img  = side ? img2  : img0;
    const float* filt = side ? filt1 : filt0;
    int x = threadIdx.x;                  // 0..511 == WW-1

    for (int j = 0; j < BAND; ++j) {
        int y = t0 + j;

        // --- in-LDS fill (bit-identical chain to fill2_k) ---
        float ax, ay, c;
        box_sum_lds(acc, rbase, y, x, ax, ay, c);
        float fx, fy;
        if (c > 0.0f) {
            fx = ax / c;
            fy = ay / c;
        } else {
            float nx = 0.0f, ny = 0.0f, den = 0.0f;
            float bx, by, bc;
            if (y > 0)      { box_sum_lds(acc, rbase, y - 1, x, bx, by, bc); if (bc > 0.0f) { nx += bx / bc; ny += by / bc; den += 1.0f; } }
            if (y < HH - 1) { box_sum_lds(acc, rbase, y + 1, x, bx, by, bc); if (bc > 0.0f) { nx += bx / bc; ny += by / bc; den += 1.0f; } }
            if (x > 0)      { box_sum_lds(acc, rbase, y, x - 1, bx, by, bc); if (bc > 0.0f) { nx += bx / bc; ny += by / bc; den += 1.0f; } }
            if (x < WW - 1) { box_sum_lds(acc, rbase, y, x + 1, bx, by, bc); if (bc > 0.0f) { nx += bx / bc; ny += by / bc; den += 1.0f; } }
            float inv = 1.0f / fmaxf(den, 1.0f);
            fx = nx * inv;
            fy = ny * inv;
        }

        // --- interp (identical body to the proven interp_k) ---
        float x2 = fminf(fmaxf((float)x + fx, 0.0f), (float)(WW - 1));
        float y2 = fminf(fmaxf((float)y + fy, 0.0f), (float)(HH - 1));
        float xff = floorf(x2), yff = floorf(y2);
        int xf = (int)xff, yf = (int)yff;
        float a  = x2 - xff;
        float bb = y2 - yff;
        float w00 = (1.0f - a) * (1.0f - bb);
        float w10 = a * (1.0f - bb);
        float w01 = (1.0f - a) * bb;
        float w11 = a * bb;

        float F[4][4];
        #pragma unroll
        for (int k = 0; k < 16; k++) {
            F[k >> 2][k & 3] = filt[((b * 16 + k) * HH + y) * WW + x];
        }
        float Cf[5][5];
        #pragma unroll
        for (int r = 0; r < 5; r++) {
            #pragma unroll
            for (int sc = 0; sc < 5; sc++) {
                float v = 0.0f;
                if (r < 4 && sc < 4)   v += w00 * F[r][sc];
                if (r < 4 && sc >= 1)  v += w10 * F[r][sc - 1];
                if (r >= 1 && sc < 4)  v += w01 * F[r - 1][sc];
                if (r >= 1 && sc >= 1) v += w11 * F[r - 1][sc - 1];
                Cf[r][sc] = v;
            }
        }
        int rows[5];
        #pragma unroll
        for (int r = 0; r < 5; r++) rows[r] = min(max(yf - 1 + r, 0), HH - 1);

        bool interior = (xf >= 1) && (xf <= WW - 4);
        if (interior) {
            int x0 = xf - 1;   // cols are x0..x0+4, all in-bounds
            #pragma unroll
            for (int ch = 0; ch < 3; ch++) {
                const float* ip = img + (b * 3 + ch) * HWP;
                float accv = 0.0f;
                #pragma unroll
                for (int r = 0; r < 5; r++) {
                    const float* rp = ip + rows[r] * WW + x0;
                    float wrow[5];
                    __builtin_memcpy(wrow, rp, 5 * sizeof(float));
                    #pragma unroll
                    for (int sc = 0; sc < 5; sc++) {
                        accv += Cf[r][sc] * wrow[sc];
                    }
                }
                unsafeAtomicAdd(&out[((b * 3 + ch) * HH + y) * WW + x], 0.5f * accv);
            }
        } else {
            int cols[5];
            #pragma unroll
            for (int sc = 0; sc < 5; sc++) cols[sc] = min(max(xf - 1 + sc, 0), WW - 1);
            #pragma unroll
            for (int ch = 0; ch < 3; ch++) {
                const float* ip = img + (b * 3 + ch) * HWP;
                float accv = 0.0f;
                #pragma unroll
                for (int r = 0; r < 5; r++) {
                    const float* rp = ip + rows[r] * WW;
                    #pragma unroll
                    for (int sc = 0; sc < 5; sc++) {
                        accv += Cf[r][sc] * rp[cols[sc]];
                    }
                }
                unsafeAtomicAdd(&out[((b * 3 + ch) * HH + y) * WW + x], 0.5f * accv);
            }
        }
    }
}

extern "C" void kernel_launch(void* const* d_in, const int* in_sizes, int n_in,
                              void* d_out, int out_size, void* d_ws, size_t ws_size,
                              hipStream_t stream) {
    const float* input0 = (const float*)d_in[0];
    const float* input2 = (const float*)d_in[1];
    const float* flow01 = (const float*)d_in[2];
    const float* flow10 = (const float*)d_in[3];
    const float* filt0  = (const float*)d_in[4];
    const float* filt1  = (const float*)d_in[5];
    float* out = (float*)d_out;

    float* ws = (float*)d_ws;
    float* Fu   = ws;                    // 4*NPIX floats: upsampled flow [side][comp][...]
    float* ovf  = ws + 4 * NPIX;         // 64 + 3*OV_CAP floats (1.57 MB) overflow list

    const int BS = 256;
    const int NBLK = (NPIX + BS - 1) / BS;

    hipMemsetAsync(out, 0, (size_t)3 * NPIX * sizeof(float), stream);
    hipMemsetAsync(ovf, 0, 256, stream);

    upsample_k<<<dim3(NBLK, 2), BS, 0, stream>>>(flow01, flow10, Fu, ovf);
    rgf_interp_k<<<dim3(2 * NB * NBANDS), 512, 0, stream>>>(
        Fu, ovf, input0, input2, filt0, filt1, out);
}

// Round 11
// 254.597 us; speedup vs baseline: 1.0497x; 1.0497x over previous
//
#include <hip/hip_runtime.h>

// Problem dims (fixed by setup_inputs)
#define HH 384
#define WW 512
#define NB 4
#define HWP (HH * WW)       // 196608
#define NPIX (NB * HWP)     // 786432
#define SH 96
#define SW 128
#define SHW (SH * SW)

// Row-banded gather parameters
#define MBOUND 24           // |fy| < 24 handled by banded gather; rest -> exact overflow list
#define BAND 6              // target rows per block (round-9 proven best)
#define NBANDS (HH / BAND)  // 64
#define NROWS (BAND + 3)    // LDS rows t0-2 .. t0+6 (halo for in-LDS fill)
#define OV_CAP 131072       // overflow record capacity (expected ~3-6K used; >20x margin)

// Phase 1: quad upsample. For 4x bilinear with align_corners=False, the x
// fractional weights are EXACT closed forms of u = x&3: sx = 0.25x - 0.375,
// so wx = {0.625, 0.875, 0.125, 0.375}[u] and ix = k-1 (u<2) else k, k=x>>2.
// One thread produces 4 consecutive outputs from 6 flow loads per component,
// with per-pixel arithmetic bit-identical to the original chain
// (same __fmul_rn(10,f)/__fsub_rn/__fmul_rn/__fadd_rn order).
__global__ __launch_bounds__(256) void upsample4_k(const float* __restrict__ flow01,
                                                   const float* __restrict__ flow10,
                                                   float* __restrict__ Fu, float* __restrict__ ovf) {
    int q = blockIdx.x * blockDim.x + threadIdx.x;   // quad index
    if (q >= NPIX / 4) return;
    int side = blockIdx.y;
    const float* flow = side ? flow10 : flow01;
    int k = q % (WW / 4);             // 0..127 == source col (center)
    int y = (q / (WW / 4)) % HH;
    int b = q / ((WW / 4) * HH);
    const float* fp = flow + b * 2 * SHW;

    // y interpolation (identical to original per-pixel chain)
    float sy = __fadd_rn(__fmul_rn((float)y, 0.25f), -0.375f);  // exact
    float fy0 = floorf(sy);
    float wy = __fsub_rn(sy, fy0);
    int iy = (int)fy0;
    int y0 = max(iy, 0), y1 = min(iy + 1, SH - 1);
    float omy = __fsub_rn(1.0f, wy);

    int cm1 = max(k - 1, 0);
    int cp1 = min(k + 1, SW - 1);

    const float wxs[4]  = {0.625f, 0.875f, 0.125f, 0.375f};   // exact
    float res[2][4];

    #pragma unroll
    for (int comp = 0; comp < 2; ++comp) {
        const float* f = fp + comp * SHW;
        float a0 = __fmul_rn(10.0f, f[y0 * SW + cm1]);
        float a1 = __fmul_rn(10.0f, f[y0 * SW + k]);
        float a2 = __fmul_rn(10.0f, f[y0 * SW + cp1]);
        float b0 = __fmul_rn(10.0f, f[y1 * SW + cm1]);
        float b1 = __fmul_rn(10.0f, f[y1 * SW + k]);
        float b2 = __fmul_rn(10.0f, f[y1 * SW + cp1]);
        #pragma unroll
        for (int u = 0; u < 4; ++u) {
            float v00 = (u < 2) ? a0 : a1;
            float v01 = (u < 2) ? a1 : a2;
            float v10 = (u < 2) ? b0 : b1;
            float v11 = (u < 2) ? b1 : b2;
            float wx = wxs[u];
            float omx = __fsub_rn(1.0f, wx);
            float w00 = __fmul_rn(omx, omy);
            float w10 = __fmul_rn(wx, omy);
            float w01 = __fmul_rn(omx, wy);
            float w11 = __fmul_rn(wx, wy);
            float s = __fmul_rn(w00, v00);
            s = __fadd_rn(s, __fmul_rn(w10, v01));
            s = __fadd_rn(s, __fmul_rn(w01, v10));
            s = __fadd_rn(s, __fmul_rn(w11, v11));
            res[comp][u] = s;
        }
    }

    int idx = b * HWP + y * WW + 4 * k;
    float* F = Fu + side * 2 * NPIX;
    *(float4*)(F + idx)        = make_float4(res[0][0], res[0][1], res[0][2], res[0][3]);
    *(float4*)(F + NPIX + idx) = make_float4(res[1][0], res[1][1], res[1][2], res[1][3]);

    // overflow detection per pixel (exact path for out-of-band rows)
    #pragma unroll
    for (int u = 0; u < 4; ++u) {
        float fx = res[0][u];
        float fy = res[1][u];
        int x = 4 * k + u;
        float x2 = __fadd_rn((float)x, fx);
        float y2 = __fadd_rn((float)y, fy);
        bool valid = (x2 >= 0.0f && x2 <= (float)(WW - 1) && y2 >= 0.0f && y2 <= (float)(HH - 1));
        bool banded = (fy >= -(float)MBOUND && fy < (float)MBOUND);
        if (valid && !banded) {
            int xf = (int)floorf(x2);
            int yf = (int)floorf(y2);
            int key = side * NPIX + b * HWP + yf * WW + xf;
            int slot = atomicAdd((int*)ovf, 1);
            if (slot >= 0 && slot < OV_CAP) {
                ((int*)ovf)[64 + slot] = key;
                ovf[64 + OV_CAP + slot] = -fx;
                ovf[64 + 2 * OV_CAP + slot] = -fy;
            }
        }
    }
}

// 2x2 weighted box-sum over the LDS band histogram == the reference's
// 4-neighbor scatter sum. Identical add order/weights to the proven global
// version; only the storage moved to LDS.
static __device__ __forceinline__ void box_sum_lds(const float (&acc)[3][NROWS][WW], int rbase,
                                                   int y, int x, float& ax, float& ay, float& c) {
    float wxs1 = (x == WW - 1) ? 2.0f : 1.0f;
    float wys1 = (y == HH - 1) ? 2.0f : 1.0f;
    float sx = 0.0f, sy = 0.0f, sc = 0.0f;
    #pragma unroll
    for (int j = 0; j < 2; j++) {
        int ey = y - 1 + j;
        if (ey < 0) continue;
        float wy = j ? wys1 : 1.0f;
        int rr = ey - rbase;   // in [0, NROWS-1] by construction
        #pragma unroll
        for (int i = 0; i < 2; i++) {
            int ex = x - 1 + i;
            if (ex < 0) continue;
            float w = wy * ((i ? wxs1 : 1.0f));   // exact
            sx += w * acc[0][rr][ex];
            sy += w * acc[1][rr][ex];
            sc += w * acc[2][rr][ex];
        }
    }
    ax = sx; ay = sy; c = sc;
}

// Phase 2 (fully fused): one block per (side, b, 6-row band), 512 threads.
// (a) Build the deposit histogram for rows [t0-2, t0+6] in LDS (LDS atomics,
// float4 scan loads: 4 px per work item), (b) replay the exact overflow
// list, (c) per pixel: in-LDS fill -> Ft, then the 4x4-filter bilinear
// interp, atomically combining 0.5*acc into out (memset-zeroed).
// LDS 55.3 KB -> 2 blocks/CU; 512 blocks = exactly 2/CU all-resident.
// Plain __launch_bounds__(512): VGPR free (~60) for load batching.
// XCD-chunked blockIdx mapping (slab = bid&7) keeps each slab L2-resident.
__global__ __launch_bounds__(512) void rgf_interp_k(const float* __restrict__ Fu,
                                                    const float* __restrict__ ovf,
                                                    const float* __restrict__ img0,
                                                    const float* __restrict__ img2,
                                                    const float* __restrict__ filt0,
                                                    const float* __restrict__ filt1,
                                                    float* __restrict__ out) {
    __shared__ float acc[3][NROWS][WW];   // 55.3 KB
    int bid = blockIdx.x;                 // 512 blocks
    int slab = bid & 7;
    int side = slab >> 2;
    int b = slab & 3;
    int t0 = (bid >> 3) * BAND;
    int rbase = t0 - 2;                   // global row of acc row 0

    const float* Fx = Fu + side * 2 * NPIX + b * HWP;
    const float* Fyp = Fx + NPIX;

    float* A = &acc[0][0][0];
    for (int k = threadIdx.x; k < 3 * NROWS * WW; k += 512) A[k] = 0.0f;
    __syncthreads();

    // sources for target rows [t0-2, t0+BAND] with floor(fy) in [-M, M-1]:
    // s in [t0-2-(M-1), t0+BAND+M]  (56 rows interior)
    int sLo = max(t0 - 2 - (MBOUND - 1), 0);
    int sHi = min(t0 + BAND + MBOUND, HH - 1);
    int nitems = (sHi - sLo + 1) * 128;   // (row, col-quad) work items
    for (int k = threadIdx.x; k < nitems; k += 512) {
        int s = sLo + (k >> 7);
        int tx = k & 127;
        int rowoff = s * WW + 4 * tx;
        float4 fxv = *(const float4*)(Fx + rowoff);
        float4 fyv = *(const float4*)(Fyp + rowoff);
        float sf = (float)s;
        #pragma unroll
        for (int u = 0; u < 4; ++u) {
            int xx = 4 * tx + u;
            float fx = (u == 0) ? fxv.x : (u == 1) ? fxv.y : (u == 2) ? fxv.z : fxv.w;
            float fy = (u == 0) ? fyv.x : (u == 1) ? fyv.y : (u == 2) ? fyv.z : fyv.w;
            float x2 = __fadd_rn((float)xx, fx);
            float y2 = __fadd_rn(sf, fy);
            if (x2 >= 0.0f && x2 <= (float)(WW - 1) && y2 >= 0.0f && y2 <= (float)(HH - 1)
                && fy >= -(float)MBOUND && fy < (float)MBOUND) {
                int yf = (int)floorf(y2);
                int r = yf - rbase;
                if (r >= 0 && r < NROWS) {
                    int xf = (int)floorf(x2);
                    atomicAdd(&acc[0][r][xf], -fx);
                    atomicAdd(&acc[1][r][xf], -fy);
                    atomicAdd(&acc[2][r][xf], 1.0f);
                }
            }
        }
    }

    // replay exact overflow records landing in [max(rbase,0), min(t0+BAND,HH-1)]
    int n = ((const int*)ovf)[0];
    n = (n < 0) ? 0 : ((n > OV_CAP) ? OV_CAP : n);
    int lo = max(rbase, 0) * WW;
    int hi = (min(t0 + BAND, HH - 1) + 1) * WW;
    int keybase = side * NPIX + b * HWP;
    for (int i = threadIdx.x; i < n; i += 512) {
        int rel = ((const int*)ovf)[64 + i] - keybase;
        if (rel >= lo && rel < hi) {
            int r = rel / WW - rbase;
            int xf = rel % WW;
            atomicAdd(&acc[0][r][xf], ovf[64 + OV_CAP + i]);
            atomicAdd(&acc[1][r][xf], ovf[64 + 2 * OV_CAP + i]);
            atomicAdd(&acc[2][r][xf], 1.0f);
        }
    }
    __syncthreads();

    // (c) per-pixel fill + interp. Thread = column x, loop j over the 6 band
    // rows. acc is read-only from here (no further syncs needed).
    const float* img  = side ? img2  : img0;
    const float* filt = side ? filt1 : filt0;
    int x = threadIdx.x;                  // 0..511 == WW-1

    for (int j = 0; j < BAND; ++j) {
        int y = t0 + j;

        // --- in-LDS fill (bit-identical chain to fill2_k) ---
        float ax, ay, c;
        box_sum_lds(acc, rbase, y, x, ax, ay, c);
        float fx, fy;
        if (c > 0.0f) {
            fx = ax / c;
            fy = ay / c;
        } else {
            float nx = 0.0f, ny = 0.0f, den = 0.0f;
            float bx, by, bc;
            if (y > 0)      { box_sum_lds(acc, rbase, y - 1, x, bx, by, bc); if (bc > 0.0f) { nx += bx / bc; ny += by / bc; den += 1.0f; } }
            if (y < HH - 1) { box_sum_lds(acc, rbase, y + 1, x, bx, by, bc); if (bc > 0.0f) { nx += bx / bc; ny += by / bc; den += 1.0f; } }
            if (x > 0)      { box_sum_lds(acc, rbase, y, x - 1, bx, by, bc); if (bc > 0.0f) { nx += bx / bc; ny += by / bc; den += 1.0f; } }
            if (x < WW - 1) { box_sum_lds(acc, rbase, y, x + 1, bx, by, bc); if (bc > 0.0f) { nx += bx / bc; ny += by / bc; den += 1.0f; } }
            float inv = 1.0f / fmaxf(den, 1.0f);
            fx = nx * inv;
            fy = ny * inv;
        }

        // --- interp (identical body to the proven interp_k) ---
        float x2 = fminf(fmaxf((float)x + fx, 0.0f), (float)(WW - 1));
        float y2 = fminf(fmaxf((float)y + fy, 0.0f), (float)(HH - 1));
        float xff = floorf(x2), yff = floorf(y2);
        int xf = (int)xff, yf = (int)yff;
        float a  = x2 - xff;
        float bb = y2 - yff;
        float w00 = (1.0f - a) * (1.0f - bb);
        float w10 = a * (1.0f - bb);
        float w01 = (1.0f - a) * bb;
        float w11 = a * bb;

        float F[4][4];
        #pragma unroll
        for (int k = 0; k < 16; k++) {
            F[k >> 2][k & 3] = filt[((b * 16 + k) * HH + y) * WW + x];
        }
        float Cf[5][5];
        #pragma unroll
        for (int r = 0; r < 5; r++) {
            #pragma unroll
            for (int sc = 0; sc < 5; sc++) {
                float v = 0.0f;
                if (r < 4 && sc < 4)   v += w00 * F[r][sc];
                if (r < 4 && sc >= 1)  v += w10 * F[r][sc - 1];
                if (r >= 1 && sc < 4)  v += w01 * F[r - 1][sc];
                if (r >= 1 && sc >= 1) v += w11 * F[r - 1][sc - 1];
                Cf[r][sc] = v;
            }
        }
        int rows[5];
        #pragma unroll
        for (int r = 0; r < 5; r++) rows[r] = min(max(yf - 1 + r, 0), HH - 1);

        bool interior = (xf >= 1) && (xf <= WW - 4);
        if (interior) {
            int x0 = xf - 1;   // cols are x0..x0+4, all in-bounds
            #pragma unroll
            for (int ch = 0; ch < 3; ch++) {
                const float* ip = img + (b * 3 + ch) * HWP;
                float accv = 0.0f;
                #pragma unroll
                for (int r = 0; r < 5; r++) {
                    const float* rp = ip + rows[r] * WW + x0;
                    float wrow[5];
                    __builtin_memcpy(wrow, rp, 5 * sizeof(float));
                    #pragma unroll
                    for (int sc = 0; sc < 5; sc++) {
                        accv += Cf[r][sc] * wrow[sc];
                    }
                }
                unsafeAtomicAdd(&out[((b * 3 + ch) * HH + y) * WW + x], 0.5f * accv);
            }
        } else {
            int cols[5];
            #pragma unroll
            for (int sc = 0; sc < 5; sc++) cols[sc] = min(max(xf - 1 + sc, 0), WW - 1);
            #pragma unroll
            for (int ch = 0; ch < 3; ch++) {
                const float* ip = img + (b * 3 + ch) * HWP;
                float accv = 0.0f;
                #pragma unroll
                for (int r = 0; r < 5; r++) {
                    const float* rp = ip + rows[r] * WW;
                    #pragma unroll
                    for (int sc = 0; sc < 5; sc++) {
                        accv += Cf[r][sc] * rp[cols[sc]];
                    }
                }
                unsafeAtomicAdd(&out[((b * 3 + ch) * HH + y) * WW + x], 0.5f * accv);
            }
        }
    }
}

extern "C" void kernel_launch(void* const* d_in, const int* in_sizes, int n_in,
                              void* d_out, int out_size, void* d_ws, size_t ws_size,
                              hipStream_t stream) {
    const float* input0 = (const float*)d_in[0];
    const float* input2 = (const float*)d_in[1];
    const float* flow01 = (const float*)d_in[2];
    const float* flow10 = (const float*)d_in[3];
    const float* filt0  = (const float*)d_in[4];
    const float* filt1  = (const float*)d_in[5];
    float* out = (float*)d_out;

    float* ws = (float*)d_ws;
    float* Fu   = ws;                    // 4*NPIX floats: upsampled flow [side][comp][...]
    float* ovf  = ws + 4 * NPIX;         // 64 + 3*OV_CAP floats (1.57 MB) overflow list

    const int BS = 256;
    const int NQBLK = (NPIX / 4 + BS - 1) / BS;   // 768 quad-blocks

    hipMemsetAsync(out, 0, (size_t)3 * NPIX * sizeof(float), stream);
    hipMemsetAsync(ovf, 0, 256, stream);

    upsample4_k<<<dim3(NQBLK, 2), BS, 0, stream>>>(flow01, flow10, Fu, ovf);
    rgf_interp_k<<<dim3(2 * NB * NBANDS), 512, 0, stream>>>(
        Fu, ovf, input0, input2, filt0, filt1, out);
}